// Round 18
// baseline (14255.997 us; speedup 1.0000x reference)
//
#include <hip/hip_runtime.h>

#define T_STEPS 256
#define H_DIM   1024
#define L_CTX   200
#define CTXD    512
#define A_DIM   512
#define G4      4096
#define KT2     3072   // W4T k-range: 1024 Uh + 1024 Ph + 1024 Hh
#define NBLK    64
#define NTHR    512

// ws offsets (floats) — per-step slots fresh (never reused), 2KB-aligned.
#define OFF_XWB    0                           // 256*4096 f32
#define OFF_CTXW   (OFF_XWB   + T_STEPS*G4)    // 200*512 f32
#define OFF_HIST   (OFF_CTXW  + L_CTX*A_DIM)   // 256*1024 f32 (write-once rows)
#define OFF_E      (OFF_HIST  + T_STEPS*H_DIM) // 256*512 f32: per-step [eC|eH]
#define OFF_CC     (OFF_E     + T_STEPS*A_DIM) // bf16 4096*200
#define OFF_HH     (OFF_CC    + G4*L_CTX/2)    // bf16 4096*256 (block-private)
#define OFF_W4TI8  (OFF_HH    + G4*T_STEPS/2)  // int8 4096*3072
#define OFF_WSC    (OFF_W4TI8 + G4*KT2/4)      // 4096 f32 per-col quant step
#define OFF_W3I8   (OFF_WSC   + G4)            // int8 1536*1024 (Wh|Whh|Whist rows)
#define OFF_WSC3   (OFF_W3I8  + 1536*H_DIM/4)  // 1536 f32 per-row quant step
#define OFF_BAR    (OFF_WSC3  + 1536)          // 64 byte-flags (one 64B line)
#define WS_FLOATS  (OFF_BAR   + 256)

__device__ __forceinline__ float sigmoidf_(float x) { return 1.f / (1.f + __expf(-x)); }
__device__ __forceinline__ float bf2f(unsigned short h) { return __uint_as_float((unsigned)h << 16); }
__device__ __forceinline__ unsigned short f2bf(float x) {
    unsigned u = __float_as_uint(x);
    return (unsigned short)((u + 0x7FFFu + ((u >> 16) & 1u)) >> 16);
}
__device__ __forceinline__ void st_ag(float* p, float v) {
    __hip_atomic_store(p, v, __ATOMIC_RELAXED, __HIP_MEMORY_SCOPE_AGENT);
}
__device__ __forceinline__ float wred(float x) {
    #pragma unroll
    for (int off = 32; off; off >>= 1) x += __shfl_down(x, off);
    return x;
}
__device__ __forceinline__ float wredmax(float x) {
    #pragma unroll
    for (int off = 32; off; off >>= 1) x = fmaxf(x, __shfl_down(x, off));
    return x;
}
// dot of 4 packed int8 (in a uint) with 4 floats
#define DOT4(W, XP, ACC)                                            \
    { int wa_ = (int)(W);                                           \
      ACC += (float)((wa_ << 24) >> 24) * (XP)[0];                  \
      ACC += (float)((wa_ << 16) >> 24) * (XP)[1];                  \
      ACC += (float)((wa_ <<  8) >> 24) * (XP)[2];                  \
      ACC += (float)( wa_        >> 24) * (XP)[3]; }

// flag barrier: 64 byte-flags in ONE 64B line; wave 0 polls (wraparound-safe)
__device__ __forceinline__ void gbar(unsigned char* bar, int b, unsigned ph) {
    __syncthreads();
    if (threadIdx.x < 64) {
        const unsigned char tgt = (unsigned char)ph;
        if (threadIdx.x == 0)
            __hip_atomic_store(bar + b, tgt, __ATOMIC_RELAXED, __HIP_MEMORY_SCOPE_AGENT);
        for (int spins = 0; spins < 40000; ++spins) {   // cap = hang insurance
            unsigned char f = __hip_atomic_load(bar + threadIdx.x, __ATOMIC_RELAXED,
                                                __HIP_MEMORY_SCOPE_AGENT);
            if (!__any((int)(signed char)(f - tgt) < 0)) break;
            __builtin_amdgcn_s_sleep(1);
        }
    }
    __syncthreads();
}

// ---------- prep kernels ----------

__global__ __launch_bounds__(256) void k_xwb(const float* __restrict__ X,
                                             const float* __restrict__ Wx,
                                             const float* __restrict__ b4,
                                             float* __restrict__ XWb) {
    int c  = blockIdx.x * 256 + threadIdx.x;
    int r0 = blockIdx.y * 8;
    float acc[8] = {0,0,0,0,0,0,0,0};
    for (int k = 0; k < 512; ++k) {
        float wv = Wx[(size_t)k * G4 + c];
        #pragma unroll
        for (int r = 0; r < 8; ++r) acc[r] += X[(r0 + r) * 512 + k] * wv;
    }
    float bb = b4[c];
    #pragma unroll
    for (int r = 0; r < 8; ++r) XWb[(size_t)(r0 + r) * G4 + c] = acc[r] + bb;
}

__global__ __launch_bounds__(256) void k_ctxw(const float* __restrict__ ctx,
                                              const float* __restrict__ Wctx,
                                              const float* __restrict__ bctx,
                                              float* __restrict__ ctxW) {
    int a  = blockIdx.x * 256 + threadIdx.x;
    int l0 = blockIdx.y * 8;
    float acc[8] = {0,0,0,0,0,0,0,0};
    for (int k = 0; k < 512; ++k) {
        float wv = Wctx[(size_t)k * A_DIM + a];
        #pragma unroll
        for (int r = 0; r < 8; ++r) acc[r] += ctx[(l0 + r) * CTXD + k] * wv;
    }
    float bb = bctx[a];
    #pragma unroll
    for (int r = 0; r < 8; ++r) ctxW[(l0 + r) * A_DIM + a] = acc[r] + bb;
}

__global__ __launch_bounds__(256) void k_cc(const float* __restrict__ ctx,
                                            const float* __restrict__ Cc,
                                            unsigned short* __restrict__ CCp) {
    int c  = blockIdx.x * 256 + threadIdx.x;
    int l0 = blockIdx.y * 8;
    float acc[8] = {0,0,0,0,0,0,0,0};
    for (int k = 0; k < 512; ++k) {
        float wv = Cc[(size_t)k * G4 + c];
        #pragma unroll
        for (int r = 0; r < 8; ++r) acc[r] += ctx[(l0 + r) * CTXD + k] * wv;
    }
    int colp = 4 * (c & 1023) + (c >> 10);
    #pragma unroll
    for (int r = 0; r < 8; ++r) CCp[(size_t)colp * L_CTX + l0 + r] = f2bf(acc[r]);
}

__global__ __launch_bounds__(256) void k_colmax(const float* __restrict__ Uh,
                                                const float* __restrict__ Ph,
                                                const float* __restrict__ Hh,
                                                float* __restrict__ wsc) {
    int c = blockIdx.x * 256 + threadIdx.x;
    float m = 0.f;
    for (int k = 0; k < 1024; ++k) {
        m = fmaxf(m, fabsf(Uh[(size_t)k * G4 + c]));
        m = fmaxf(m, fabsf(Ph[(size_t)k * G4 + c]));
        m = fmaxf(m, fabsf(Hh[(size_t)k * G4 + c]));
    }
    int colp = 4 * (c & 1023) + (c >> 10);
    wsc[colp] = fmaxf(m, 1e-20f) / 127.f;
}

__global__ __launch_bounds__(256) void k_packW4i8(const float* __restrict__ Uh,
                                                  const float* __restrict__ Ph,
                                                  const float* __restrict__ Hh,
                                                  const float* __restrict__ wsc,
                                                  signed char* __restrict__ W8) {
    __shared__ float tile[32][33];
    const int k0 = blockIdx.x * 32, d0 = blockIdx.y * 32, q = blockIdx.z;
    const int x = threadIdx.x & 31, yy = threadIdx.x >> 5;
    const int c = q * 1024 + d0 + x;
    #pragma unroll
    for (int i = 0; i < 32; i += 8) {
        int ka = k0 + yy + i;
        const float* src; int kk;
        if (ka < 1024)      { src = Uh; kk = ka; }
        else if (ka < 2048) { src = Ph; kk = ka - 1024; }
        else                { src = Hh; kk = ka - 2048; }
        tile[yy + i][x] = src[(size_t)kk * G4 + c];
    }
    __syncthreads();
    #pragma unroll
    for (int i = 0; i < 32; i += 8) {
        int dd = yy + i;
        int col = 4 * (d0 + dd) + q;
        float r = 1.f / wsc[col];
        float qv = rintf(tile[x][dd] * r);
        qv = fminf(fmaxf(qv, -127.f), 127.f);
        W8[(size_t)col * KT2 + k0 + x] = (signed char)qv;
    }
}

// per-row quant step for [Wh|Whh|Whist]^T: row j<512:Wh col j, etc. grid(2,3)
__global__ __launch_bounds__(256) void k_w3max(const float* __restrict__ Wh,
                                               const float* __restrict__ Whh,
                                               const float* __restrict__ Whist,
                                               float* __restrict__ wsc3) {
    int c = blockIdx.x * 256 + threadIdx.x;     // [0,512)
    const float* S = (blockIdx.y == 0) ? Wh : (blockIdx.y == 1) ? Whh : Whist;
    float m = 0.f;
    for (int k = 0; k < 1024; ++k) m = fmaxf(m, fabsf(S[(size_t)k * 512 + c]));
    wsc3[blockIdx.y * 512 + c] = fmaxf(m, 1e-20f) / 127.f;
}

// pack [Wh|Whh|Whist] -> W3[j][k] int8 rows. grid(32,16,3)
__global__ __launch_bounds__(256) void k_packW3i8(const float* __restrict__ Wh,
                                                  const float* __restrict__ Whh,
                                                  const float* __restrict__ Whist,
                                                  const float* __restrict__ wsc3,
                                                  signed char* __restrict__ W3) {
    __shared__ float tile[32][33];
    const int k0 = blockIdx.x * 32, c0 = blockIdx.y * 32, s = blockIdx.z;
    const float* S = (s == 0) ? Wh : (s == 1) ? Whh : Whist;
    const int x = threadIdx.x & 31, yy = threadIdx.x >> 5;
    #pragma unroll
    for (int i = 0; i < 32; i += 8)
        tile[yy + i][x] = S[(size_t)(k0 + yy + i) * 512 + c0 + x];
    __syncthreads();
    #pragma unroll
    for (int i = 0; i < 32; i += 8) {
        int dd = yy + i;
        int row = s * 512 + c0 + dd;
        float r = 1.f / wsc3[row];
        float qv = rintf(tile[x][dd] * r);
        qv = fminf(fmaxf(qv, -127.f), 127.f);
        W3[(size_t)row * H_DIM + k0 + x] = (signed char)qv;
    }
}

// ---------- persistent recurrent kernel (64 blocks x 512 threads) ----------

struct LP {
    const float *ctx, *c0, *v, *v2, *bv, *bv2, *bhist, *h0;
    const int* parent;
    float* ws;
    float* out;
};

__global__ __launch_bounds__(NTHR) void lstm_loop(LP p) {
    const int b    = blockIdx.x;
    const int tid  = threadIdx.x;
    const int lane = tid & 63, wv = tid >> 6;   // 8 waves

    float* XWb  = p.ws + OFF_XWB;
    float* ctxW = p.ws + OFF_CTXW;
    float* hist = p.ws + OFF_HIST;
    float* E    = p.ws + OFF_E;
    const unsigned short* CCp = (const unsigned short*)(p.ws + OFF_CC);
    unsigned short*       HHp = (unsigned short*)(p.ws + OFF_HH);
    const unsigned char*  W4I = (const unsigned char*)(p.ws + OFF_W4TI8);
    const float*          WSC = p.ws + OFF_WSC;
    const unsigned char*  W3I = (const unsigned char*)(p.ws + OFF_W3I8);
    const float*          WSC3 = p.ws + OFF_WSC3;
    unsigned char* bar = (unsigned char*)(p.ws + OFF_BAR);

    __shared__ float xs[2048];        // [h_prev | par]
    __shared__ float uw_[512];        // replicated u (eC) or w (eH)
    __shared__ float myHW[8][512];    // eH: own 8 histW rows (16 KB)
    __shared__ float vs_[512], v2s_[512];
    __shared__ float aC[256], aH[256];
    __shared__ float red[16], sc[4], zs1[64], zs[64];

    vs_[tid] = p.v[tid];  v2s_[tid] = p.v2[tid];
    const float bv = p.bv[0], bv2 = p.bv2[0];
    __syncthreads();

    const int grp = tid >> 3;          // local col [0,64)
    const int sub = tid & 7;
    const uint2* Wcol = (const uint2*)(W4I + (size_t)(b * 64 + grp) * KT2);
    const float  wscl = WSC[b * 64 + grp];
    const unsigned short* ccC = CCp + (size_t)(b * 64 + grp) * L_CTX;
    unsigned short*       hhC = HHp + (size_t)(b * 64 + grp) * T_STEPS;
    // replicated-projection row for this thread
    const bool isC = (b < 25), isH = (b >= 32);
    const int  myrow = isC ? tid : 512 + tid;
    const uint4* myRp = (const uint4*)(W3I + (size_t)myrow * H_DIM);
    const float  mySc = WSC3[myrow];
    const float  myB  = isH ? p.bhist[tid] : 0.f;
    const uint4* owRp = (const uint4*)(W3I + (size_t)(1024 + tid) * H_DIM);
    const float  owSc = WSC3[1024 + tid];

    unsigned ph = 1;

    for (int t = 0; t < T_STEPS; ++t) {
        // ======== A: stage h/par, replicated u|w (+owner histW row), logits,
        //             hh row t-1, z-partial ========
        {
            float hv0, hv1;
            if (t == 0) { hv0 = p.h0[tid]; hv1 = p.h0[512 + tid]; }
            else { hv0 = hist[(size_t)(t - 1) * H_DIM + tid];          // cold cached
                   hv1 = hist[(size_t)(t - 1) * H_DIM + 512 + tid]; }
            xs[tid] = hv0; xs[512 + tid] = hv1;
            if (t == 0) { xs[1024 + tid] = 0.f; xs[1536 + tid] = 0.f; }
            else {
                const int pt = p.parent[t];
                if (pt == t - 1) { xs[1024 + tid] = hv0; xs[1536 + tid] = hv1; }
                else { xs[1024 + tid] = hist[(size_t)pt * H_DIM + tid];
                       xs[1536 + tid] = hist[(size_t)pt * H_DIM + 512 + tid]; }
            }
        }
        __syncthreads();

        // replicated projection: thread tid -> dim tid (int8 1024-dot)
        if (isC || isH) {
            float a0 = 0.f, a1 = 0.f;
            #pragma unroll 8
            for (int i = 0; i < 64; ++i) {
                uint4 q = myRp[i];
                const float* x = xs + i * 16;
                DOT4(q.x, x,      a0); DOT4(q.y, x + 4,  a1);
                DOT4(q.z, x + 8,  a0); DOT4(q.w, x + 12, a1);
            }
            uw_[tid] = (a0 + a1) * mySc + myB;
            // owner of histW row t-1 computes it (rotating +1 block skew)
            if (isH && t >= 1 && ((t - 1) >> 3) == b - 32) {
                float c0a = 0.f, c1a = 0.f;
                #pragma unroll 8
                for (int i = 0; i < 64; ++i) {
                    uint4 q = owRp[i];
                    const float* x = xs + i * 16;
                    DOT4(q.x, x,      c0a); DOT4(q.y, x + 4,  c1a);
                    DOT4(q.z, x + 8,  c0a); DOT4(q.w, x + 12, c1a);
                }
                myHW[(t - 1) & 7][tid] = (c0a + c1a) * owSc;
            }
        }
        __syncthreads();

        // logits (8 per block)
        {
            const int i0 = lane * 8;
            if (isC) {
                const int idx = b * 8 + wv;        // [0,200)
                const float4* cw = (const float4*)(ctxW + (size_t)idx * A_DIM + i0);
                float4 ca = cw[0], cb = cw[1];
                float e = tanhf(ca.x + uw_[i0+0]) * vs_[i0+0]
                        + tanhf(ca.y + uw_[i0+1]) * vs_[i0+1]
                        + tanhf(ca.z + uw_[i0+2]) * vs_[i0+2]
                        + tanhf(ca.w + uw_[i0+3]) * vs_[i0+3]
                        + tanhf(cb.x + uw_[i0+4]) * vs_[i0+4]
                        + tanhf(cb.y + uw_[i0+5]) * vs_[i0+5]
                        + tanhf(cb.z + uw_[i0+6]) * vs_[i0+6]
                        + tanhf(cb.w + uw_[i0+7]) * vs_[i0+7];
                e = wred(e);
                if (lane == 0) st_ag(E + (size_t)t * A_DIM + idx, e + bv);
            } else if (isH) {
                const int j = (b - 32) * 8 + wv;   // [0,256)
                if (j < t) {
                    const float* hw = myHW[wv];
                    float e = tanhf(hw[i0+0] + uw_[i0+0]) * v2s_[i0+0]
                            + tanhf(hw[i0+1] + uw_[i0+1]) * v2s_[i0+1]
                            + tanhf(hw[i0+2] + uw_[i0+2]) * v2s_[i0+2]
                            + tanhf(hw[i0+3] + uw_[i0+3]) * v2s_[i0+3]
                            + tanhf(hw[i0+4] + uw_[i0+4]) * v2s_[i0+4]
                            + tanhf(hw[i0+5] + uw_[i0+5]) * v2s_[i0+5]
                            + tanhf(hw[i0+6] + uw_[i0+6]) * v2s_[i0+6]
                            + tanhf(hw[i0+7] + uw_[i0+7]) * v2s_[i0+7];
                    e = wred(e);
                    if (lane == 0) st_ag(E + (size_t)t * A_DIM + 256 + j, e + bv2);
                }
            }
        }

        // hh[col][t-1] = h_{t-1} . Hh[:,col] (block-private, int8)
        if (t >= 1) {
            float g0 = 0.f, g1 = 0.f;
            #pragma unroll 8
            for (int i = 0; i < 16; ++i) {
                const int c2 = 256 + i * 8 + sub;
                uint2 w = Wcol[c2];
                const float* xk = xs + (c2 - 256) * 8;
                DOT4(w.x, xk, g0); DOT4(w.y, xk + 4, g1);
            }
            float hv = (g0 + g1) * wscl;
            hv += __shfl_down(hv, 4, 8);
            hv += __shfl_down(hv, 2, 8);
            hv += __shfl_down(hv, 1, 8);
            if (sub == 0) hhC[t - 1] = f2bf(hv);
        }

        // heavy int8 z-partial (Uh,Ph over [h|par]) -> park in zs1
        {
            float g0 = 0.f, g1 = 0.f;
            #pragma unroll 8
            for (int i = 0; i < 32; ++i) {
                const int c = i * 8 + sub;
                uint2 w = Wcol[c];
                const float* xk = xs + c * 8;
                DOT4(w.x, xk, g0); DOT4(w.y, xk + 4, g1);
            }
            float zp = (g0 + g1) * wscl;
            zp += __shfl_down(zp, 4, 8);
            zp += __shfl_down(zp, 2, 8);
            zp += __shfl_down(zp, 1, 8);
            if (sub == 0) zs1[grp] = zp;
        }
        gbar(bar, b, ph++);  // S1

        // ======== B: replicated softmax + attn + gates + outputs ========
        if (tid < L_CTX) aC[tid] = E[(size_t)t * A_DIM + tid];          // cold cached
        if (tid < t)     aH[tid] = E[(size_t)t * A_DIM + 256 + tid];    // cold cached
        __syncthreads();
        {
            float pC = (tid < L_CTX) ? aC[tid] : -3e38f;
            float pH = (tid < t)     ? aH[tid] : -3e38f;
            pC = wredmax(pC); pH = wredmax(pH);
            if (lane == 0) { red[wv] = pC; red[8 + wv] = pH; }
            __syncthreads();
            if (tid == 0) { float m = -3e38f; for (int g = 0; g < 8; ++g) m = fmaxf(m, red[g]); sc[0] = m; }
            if (tid == 1) { float m = -3e38f; for (int g = 0; g < 8; ++g) m = fmaxf(m, red[8 + g]); sc[1] = m; }
            __syncthreads();
            const float mC = sc[0], mH = sc[1];
            float sCp = 0.f, sHp = 0.f;
            if (tid < L_CTX) { float x = __expf(aC[tid] - mC); aC[tid] = x; sCp = x; }
            if (tid < t)     { float x = __expf(aH[tid] - mH); aH[tid] = x; sHp = x; }
            sCp = wred(sCp); sHp = wred(sHp);
            if (lane == 0) { red[wv] = sCp; red[8 + wv] = sHp; }
            __syncthreads();
            if (tid == 0) { float s = 0.f; for (int g = 0; g < 8; ++g) s += red[g]; sc[2] = s; }
            if (tid == 1) { float s = 0.f; for (int g = 0; g < 8; ++g) s += red[8 + g]; sc[3] = s; }
            __syncthreads();
            const float rC = 1.f / sc[2];
            const float rH = (t > 0) ? 1.f / sc[3] : 0.f;

            float attc = 0.f, atth = 0.f;
            for (int l = sub; l < L_CTX; l += 8) attc += aC[l] * bf2f(ccC[l]);
            for (int j = sub; j < t; j += 8)     atth += aH[j] * bf2f(hhC[j]);
            float attp = attc * rC + atth * rH;
            attp += __shfl_down(attp, 4, 8);
            attp += __shfl_down(attp, 2, 8);
            attp += __shfl_down(attp, 1, 8);
            if (sub == 0) zs[grp] = zs1[grp] + attp;
            __syncthreads();
            if (tid < 16) {
                const int d = b * 16 + tid;
                float zi = zs[4 * tid + 0] + XWb[(size_t)t * G4 + 0 * 1024 + d];
                float zf = zs[4 * tid + 1] + XWb[(size_t)t * G4 + 1 * 1024 + d];
                float zc = zs[4 * tid + 2] + XWb[(size_t)t * G4 + 2 * 1024 + d];
                float zo = zs[4 * tid + 3] + XWb[(size_t)t * G4 + 3 * 1024 + d];
                float cn = sigmoidf_(zf) * p.c0[d] + sigmoidf_(zi) * tanhf(zc);
                float hn = sigmoidf_(zo) * tanhf(cn);
                st_ag(hist + (size_t)t * H_DIM + d, hn);
                p.out[(size_t)t * H_DIM + d] = hn;
            }
            // ctx_vec output: dim d = b*8+wv; cached column reads of ctx
            {
                const int d = b * 8 + wv;
                float s = 0.f;
                for (int l = lane; l < L_CTX; l += 64)
                    s += aC[l] * p.ctx[(size_t)l * CTXD + d];
                s = wred(s);
                if (lane == 0)
                    p.out[(size_t)T_STEPS * H_DIM + (size_t)t * CTXD + d] = s * rC;
            }
        }
        if (t == T_STEPS - 1) break;
        gbar(bar, b, ph++);  // S2 (h_t published)
    }
}

// ---------- host ----------

extern "C" void kernel_launch(void* const* d_in, const int* in_sizes, int n_in,
                              void* d_out, int out_size, void* d_ws, size_t ws_size,
                              hipStream_t stream) {
    if (ws_size < (size_t)WS_FLOATS * sizeof(float)) return;  // OOB insurance

    const float* X      = (const float*)d_in[0];
    const float* ctx    = (const float*)d_in[1];
    const float* h0     = (const float*)d_in[2];
    const float* c0     = (const float*)d_in[3];
    const int*   parent = (const int*)  d_in[4];
    const float* Wx     = (const float*)d_in[5];
    const float* Uh     = (const float*)d_in[6];
    const float* Cc     = (const float*)d_in[7];
    const float* Ph     = (const float*)d_in[8];
    const float* Hh     = (const float*)d_in[9];
    const float* b4     = (const float*)d_in[10];
    const float* Wctx   = (const float*)d_in[11];
    const float* bctx   = (const float*)d_in[12];
    const float* Wh     = (const float*)d_in[13];
    const float* v      = (const float*)d_in[14];
    const float* bv     = (const float*)d_in[15];
    const float* Whist  = (const float*)d_in[16];
    const float* bhist  = (const float*)d_in[17];
    const float* Whh    = (const float*)d_in[18];
    const float* v2     = (const float*)d_in[19];
    const float* bv2    = (const float*)d_in[20];
    float* ws  = (float*)d_ws;
    float* out = (float*)d_out;

    // zero barrier flags every call (deterministic across graph replays)
    hipMemsetAsync((char*)d_ws + (size_t)OFF_BAR * sizeof(float), 0, 1024, stream);

    hipLaunchKernelGGL(k_xwb,      dim3(16, 32),    dim3(256), 0, stream, X,   Wx,   b4,   ws + OFF_XWB);
    hipLaunchKernelGGL(k_ctxw,     dim3(2, 25),     dim3(256), 0, stream, ctx, Wctx, bctx, ws + OFF_CTXW);
    hipLaunchKernelGGL(k_cc,       dim3(16, 25),    dim3(256), 0, stream, ctx, Cc,
                       (unsigned short*)(ws + OFF_CC));
    hipLaunchKernelGGL(k_colmax,   dim3(16),        dim3(256), 0, stream, Uh, Ph, Hh, ws + OFF_WSC);
    hipLaunchKernelGGL(k_packW4i8, dim3(96, 32, 4), dim3(256), 0, stream, Uh, Ph, Hh,
                       ws + OFF_WSC, (signed char*)(ws + OFF_W4TI8));
    hipLaunchKernelGGL(k_w3max,    dim3(2, 3),      dim3(256), 0, stream, Wh, Whh, Whist, ws + OFF_WSC3);
    hipLaunchKernelGGL(k_packW3i8, dim3(32, 16, 3), dim3(256), 0, stream, Wh, Whh, Whist,
                       ws + OFF_WSC3, (signed char*)(ws + OFF_W3I8));

    LP p{ctx, c0, v, v2, bv, bv2, bhist, h0, parent, ws, out};
    hipLaunchKernelGGL(lstm_loop, dim3(NBLK), dim3(NTHR), 0, stream, p);
}